// Round 15
// baseline (55.454 us; speedup 1.0000x reference)
//
#include <hip/hip_runtime.h>

#define DZ 512
#define DT 66048
#define NH 4128  // 16-col half-tiles
#define SV_JITTER 1e-4f

typedef __attribute__((ext_vector_type(8))) short bf8;
typedef __attribute__((ext_vector_type(4))) short bf4;
typedef __attribute__((ext_vector_type(4))) float f4;

__device__ __forceinline__ short f2bf(float f) {
  unsigned u = __builtin_bit_cast(unsigned, f);
  return (short)((u + 0x7FFFu + ((u >> 16) & 1u)) >> 16);
}

__device__ __forceinline__ bf8 cvt8(float4 a, float4 b) {
  bf8 r = { f2bf(a.x), f2bf(a.y), f2bf(a.z), f2bf(a.w),
            f2bf(b.x), f2bf(b.y), f2bf(b.z), f2bf(b.w) };
  return r;
}

// tril/jitter cvt: element t has k-index kbase+t
__device__ __forceinline__ bf8 cvt8_tril(float4 x, float4 y, int kbase, int diag) {
  float v[8] = {x.x, x.y, x.z, x.w, y.x, y.y, y.z, y.w};
  bf8 r;
  #pragma unroll
  for (int t = 0; t < 8; ++t) {
    int k = kbase + t;
    float val = (k < diag) ? v[t] : ((k == diag) ? v[t] + SV_JITTER : 0.f);
    r[t] = f2bf(val);
  }
  return r;
}

// 256 blocks (1/CU) x 512 threads (8 waves). LDS = 160KB exactly:
//   Afrag 128KB: eps_z bf16 frag layout (region kk*8+mi, slot=lane), staged ONCE.
//   Bh[2] 2x16KB: ping-pong 16-col B half-panels, row-major [16][512] bf16,
//                 16B-slot XOR swizzle, tril/jitter baked at stage time.
// Half h = 16 output cols; block b handles h = b+256j (j<17 for b<32 else 16).
// Pipeline per half (ONE barrier): write buf^1 (regs from last iter; waits
// only own loads) -> issue loads h+2 (contiguous 32KB slab, 1KB/wave-instr
// sequential bursts) -> diag loads h+1 -> compute buf (pure LDS+MFMA) ->
// float4 store -> barrier.
// SWAPPED mfma(bf, af): D m-index = col, n-index = sample -> lane holds 4
// consecutive cols of sample 16wv+lcol -> single float4 store per lane.
__global__ __launch_bounds__(512, 2)
void sv_kernel(const float* __restrict__ mv, const float* __restrict__ Lz,
               const float* __restrict__ Ly, const float* __restrict__ Lyz,
               const float* __restrict__ eps, float* __restrict__ out) {
  __shared__ short Afrag[128 * 512];  // 128 KB
  __shared__ short Bh[2][16 * 512];   // 2 x 16 KB

  const int tid = threadIdx.x;
  const int lane = tid & 63;
  const int wv = tid >> 6;  // 0..7 = sample group (rows 16wv..+15)
  const int lcol = lane & 15;
  const int q = lane >> 4;
  const int b = blockIdx.x;

  float4 sv[4];  // staged half-panel floats (16 VGPR), static indices only
  auto sissue = [&](int h) {
    const float* Ls = (h < 32) ? (Lz + (size_t)(16 * h) * DZ)
                               : (Lyz + (size_t)(16 * h) * DZ - (size_t)DZ * DZ);
    #pragma unroll
    for (int i = 0; i < 4; ++i)
      sv[i] = *(const float4*)(Ls + (size_t)4 * (i * 512 + tid));
  };
  // float4 f: row ro=f>>7 (2KB fp32 rows), c4=f&127; bf16 dest 8B at
  // ro*1024 + ((s16 ^ (ro&7))<<4) + (c4&1)*8, s16=c4>>1  (R13-proven).
  auto swrite = [&](int h, short* buf) {
    #pragma unroll
    for (int i = 0; i < 4; ++i) {
      const int f = i * 512 + tid;
      const int ro = f >> 7;
      const int c4 = f & 127;
      const float v[4] = {sv[i].x, sv[i].y, sv[i].z, sv[i].w};
      bf4 w;
      if (h < 32) {  // z half: tril + jitter baked in
        const int gcol = 16 * h + ro;
        #pragma unroll
        for (int t = 0; t < 4; ++t) {
          const int k = 4 * c4 + t;
          const float val =
              (k < gcol) ? v[t] : ((k == gcol) ? v[t] + SV_JITTER : 0.f);
          w[t] = f2bf(val);
        }
      } else {
        #pragma unroll
        for (int t = 0; t < 4; ++t) w[t] = f2bf(v[t]);
      }
      const int off = (ro << 10) + ((((c4 >> 1) ^ (ro & 7))) << 4) + ((c4 & 1) << 3);
      *(bf4*)((char*)buf + off) = w;
    }
  };
  auto readB = [&](const short* buf, int kk) -> bf8 {
    const int off = (lcol << 10) + ((((kk << 2) + q) ^ (lcol & 7)) << 4);
    return *(const bf8*)((const char*)buf + off);
  };
  auto diag_load = [&](int h, float4& ax, float4& ay, float4& bx, float4& by) {
    const int nb = (16 * h - DZ) >> 5;  // 32x32 Ly block
    const int i0 = (16 * h) & 16;       // half's base row within block
    const float* pa =
        eps + (size_t)(16 * wv + lcol) * DT + DZ + (size_t)nb * 32 + 8 * q;
    ax = *(const float4*)pa; ay = *(const float4*)(pa + 4);
    const float* pb = Ly + ((size_t)nb * 32 + i0 + lcol) * 32 + 8 * q;
    bx = *(const float4*)pb; by = *(const float4*)(pb + 4);
  };

  const int nh = (b < 32) ? 17 : 16;

  // ---- prologue: panel(h0) stream first (oldest), then Afrag stage-once
  sissue(b);
  {  // eps_z -> Afrag: region r = kk*8+mi, slot=lane (R13-proven)
    const int slot = lane;
    const int r0 = wv * 16;
    #pragma unroll 4
    for (int i = 0; i < 16; ++i) {
      const int r = r0 + i;  // mi=r&7, kk=r>>3
      const float* p = eps + (size_t)(16 * (r & 7) + (slot & 15)) * DT +
                       (r >> 3) * 32 + (slot >> 4) * 8;
      const float4 x = *(const float4*)p;
      const float4 y = *(const float4*)(p + 4);
      *(bf8*)&Afrag[r * 512 + slot * 8] = cvt8(x, y);
    }
  }
  swrite(b, Bh[0]);      // waits own panel loads
  if (nh > 1) sissue(b + 256);
  float4 cdax{}, cday{}, cdbx{}, cdby{};
  if (b >= 32) diag_load(b, cdax, cday, cdbx, cdby);
  __syncthreads();

  #pragma unroll 1
  for (int j = 0; j < 17; ++j) {
    if (j >= nh) break;
    const int h = b + 256 * j;
    const bool isz = (h < 32);

    // 1. write next half-panel (regs loaded last iter; other buffer, whose
    //    readers all finished before the previous barrier)
    if (j + 1 < nh) swrite(b + 256 * (j + 1), Bh[(j + 1) & 1]);
    // 2. issue loads for half j+2 (sequential 1KB bursts)
    if (j + 2 < nh) sissue(b + 256 * (j + 2));
    // 3. diag loads for half j+1 (always a y half)
    float4 ndax{}, nday{}, ndbx{}, ndby{};
    if (j + 1 < nh) diag_load(b + 256 * (j + 1), ndax, nday, ndbx, ndby);

    // 4. compute: pure LDS + MFMA (swapped operands)
    const short* buf = Bh[j & 1];
    f4 acc = f4{0.f, 0.f, 0.f, 0.f};
    #pragma unroll
    for (int kk = 0; kk < 16; ++kk) {
      const bf8 af = *(const bf8*)&Afrag[(kk * 8 + wv) * 512 + lane * 8];
      const bf8 bf = readB(buf, kk);
      acc = __builtin_amdgcn_mfma_f32_16x16x32_bf16(bf, af, acc, 0, 0, 0);
    }
    if (!isz) {  // block-diag einsum step
      const bf8 afd = cvt8(cdax, cday);
      const int i0 = (16 * h) & 16;
      const bf8 dbf = cvt8_tril(cdbx, cdby, 8 * q, i0 + lcol);
      acc = __builtin_amdgcn_mfma_f32_16x16x32_bf16(dbf, afd, acc, 0, 0, 0);
    }

    // 5. epilogue: lane = sample 16wv+lcol, cols 16h+4q..+3 -> one float4
    {
      const int c0 = 16 * h + 4 * q;
      const float4 m4 = *(const float4*)(mv + c0);
      float4 o;
      o.x = acc[0] + m4.x; o.y = acc[1] + m4.y;
      o.z = acc[2] + m4.z; o.w = acc[3] + m4.w;
      *(float4*)(out + (size_t)(16 * wv + lcol) * DT + c0) = o;
    }

    // 6. rotate diag pipeline, end-of-half barrier
    cdax = ndax; cday = nday; cdbx = ndbx; cdby = ndby;
    __syncthreads();
  }
}

extern "C" void kernel_launch(void* const* d_in, const int* in_sizes, int n_in,
                              void* d_out, int out_size, void* d_ws, size_t ws_size,
                              hipStream_t stream) {
  const float* m   = (const float*)d_in[0];
  const float* Lz  = (const float*)d_in[1];
  const float* Ly  = (const float*)d_in[2];
  const float* Lyz = (const float*)d_in[3];
  const float* eps = (const float*)d_in[4];
  float* out = (float*)d_out;
  sv_kernel<<<dim3(256), dim3(512), 0, stream>>>(m, Lz, Ly, Lyz, eps, out);
}